// Round 1
// baseline (698.934 us; speedup 1.0000x reference)
//
#include <hip/hip_runtime.h>
#include <hip/hip_bf16.h>

// GCN_large R5: full 8-wave utilization in tail phases.
// Phases 1-2 keep the fused proj->agg (same-wave handoff, no barrier).
// Phases 3-4 previously ran on 4 / 2 waves (half / three-quarters of the
// block idle at 1 block/CU occupancy); now split the node dimension across
// waves (p3: ntile=w&3, node-half=w>>2; p4: ntile=w&1, node-quarter=w>>1)
// with one barrier between proj and agg (fusion invariant no longer holds).
// Layouts unchanged:
//   Xs [112][136] bf16 : X rows, cols 112..127 zeroed (K-pad)
//   hT [256][136] bf16 : h feature-major [feat][node], cols 112..127 zeroed
//   aB [112][264] bf16 : a node-major [node][feat]

#define NODE 112
#define NBATCH 4096
#define SXS 136
#define SHT 136
#define SAB 264
#define HT_OFF (112*SXS)                 // 15232
#define AB_OFF (HT_OFF + 256*SHT)        // 50048
#define SMEM_BYTES ((AB_OFF + 112*SAB)*2)  // 159232 B

typedef float  f4v   __attribute__((ext_vector_type(4)));
typedef float  f16v  __attribute__((ext_vector_type(16)));
typedef __bf16 bf8v  __attribute__((ext_vector_type(8)));
typedef short  s8v   __attribute__((ext_vector_type(8)));
typedef unsigned short ushort_t;

__device__ __forceinline__ ushort_t f2bf(float f) {
  union { float f; unsigned u; } v; v.f = f;
  unsigned r = v.u + 0x7FFFu + ((v.u >> 16) & 1u);   // RNE
  return (ushort_t)(r >> 16);
}
__device__ __forceinline__ float bf2f(ushort_t h) {
  union { unsigned u; float f; } v; v.u = ((unsigned)h) << 16; return v.f;
}
__device__ __forceinline__ unsigned pk2(float a, float b) {
  return (unsigned)f2bf(a) | ((unsigned)f2bf(b) << 16);
}
__device__ __forceinline__ bf8v ld_frag(const ushort_t* p) {
  s8v t = *(const s8v*)p;
  return __builtin_bit_cast(bf8v, t);
}
#define MFMA32(a,b,c) __builtin_amdgcn_mfma_f32_32x32x16_bf16((a),(b),(c),0,0,0)
#define MFMA16(a,b,c) __builtin_amdgcn_mfma_f32_16x16x32_bf16((a),(b),(c),0,0,0)

// proj: hT[feat][node] = relu(a . W^T + bias). Wave handles n-tile `ntile`
// and MCNT main 32-node tiles starting at node tile mBase, plus (if TAIL)
// the 16-node tail (96..111) via 16x16x32 (K zero-padded).
template<int KS, int KC, int SA_, int MCNT, bool TAIL>
__device__ __forceinline__ void proj_part(
    const ushort_t* aSrc, const ushort_t* __restrict__ Wg, int WK,
    const float* __restrict__ bias, ushort_t* hDst, int ntile, int mBase,
    int lane)
{
  const int l31 = lane & 31, h32 = lane >> 5;
  const int l15 = lane & 15, q4 = lane >> 4;

  f16v acc[MCNT ? MCNT : 1];
  #pragma unroll
  for (int m=0;m<MCNT;m++)
    #pragma unroll
    for (int r=0;r<16;r++) acc[m][r] = 0.f;

  if (MCNT > 0) {
    const ushort_t* aP = aSrc + (mBase*32 + l31)*SA_ + h32*8;
    const ushort_t* bP = Wg + (ntile*32 + l31)*WK + h32*8;
    #pragma unroll
    for (int ks=0; ks<KS; ks++) {
      bf8v B = ld_frag(bP + ks*16);
      #pragma unroll
      for (int m=0;m<MCNT;m++)
        acc[m] = MFMA32(ld_frag(aP + m*32*SA_ + ks*16), B, acc[m]);
    }
  }

  f4v at0 = (f4v){0.f,0.f,0.f,0.f}, at1 = (f4v){0.f,0.f,0.f,0.f};
  if (TAIL) {
    const ushort_t* aT  = aSrc + (96 + l15)*SA_ + q4*8;
    const ushort_t* bT0 = Wg + (ntile*32 + l15)*WK + q4*8;
    const ushort_t* bT1 = bT0 + 16*WK;
    #pragma unroll
    for (int kc=0; kc<KC; kc++) {
      bf8v At = ld_frag(aT + kc*32);
      at0 = MFMA16(At, ld_frag(bT0 + kc*32), at0);
      at1 = MFMA16(At, ld_frag(bT1 + kc*32), at1);
    }
  }

  if (MCNT > 0) {
    float bv = bias[ntile*32 + l31];
    ushort_t* hrow = hDst + (ntile*32 + l31)*SHT;
    #pragma unroll
    for (int m=0;m<MCNT;m++)
      #pragma unroll
      for (int q=0;q<4;q++) {
        float v0=acc[m][4*q+0]+bv; v0=v0>0.f?v0:0.f;
        float v1=acc[m][4*q+1]+bv; v1=v1>0.f?v1:0.f;
        float v2=acc[m][4*q+2]+bv; v2=v2>0.f?v2:0.f;
        float v3=acc[m][4*q+3]+bv; v3=v3>0.f?v3:0.f;
        uint2 pv; pv.x = pk2(v0,v1); pv.y = pk2(v2,v3);
        *(uint2*)(hrow + (mBase+m)*32 + 8*q + 4*h32) = pv;
      }
  }
  if (TAIL) {
    #pragma unroll
    for (int s=0;s<2;s++) {
      const f4v& a = s ? at1 : at0;
      float bv = bias[ntile*32 + s*16 + l15];
      float v0=a[0]+bv; v0=v0>0.f?v0:0.f;
      float v1=a[1]+bv; v1=v1>0.f?v1:0.f;
      float v2=a[2]+bv; v2=v2>0.f?v2:0.f;
      float v3=a[3]+bv; v3=v3>0.f?v3:0.f;
      uint2 pv; pv.x = pk2(v0,v1); pv.y = pk2(v2,v3);
      *(uint2*)(hDst + (ntile*32 + s*16 + l15)*SHT + 96 + 4*q4) = pv;
    }
  }
}

// agg: aB[node][feat] = X . h, feat-tile `mt`, NCNT main 32-node tiles
// starting at node tile nBase, plus (if TAIL) node rows 96..111.
template<int NCNT, bool TAIL>
__device__ __forceinline__ void agg_part(
    const ushort_t* hS, const ushort_t* Xs_, ushort_t* aDst, int mt,
    int nBase, int lane)
{
  const int l31 = lane & 31, h32 = lane >> 5;
  const int l15 = lane & 15, q4 = lane >> 4;

  f16v acc[NCNT ? NCNT : 1];
  #pragma unroll
  for (int n=0;n<NCNT;n++)
    #pragma unroll
    for (int r=0;r<16;r++) acc[n][r] = 0.f;

  if (NCNT > 0) {
    const ushort_t* aP = hS + (mt*32 + l31)*SHT + h32*8;
    const ushort_t* bP = Xs_ + (nBase*32 + l31)*SXS + h32*8;
    #pragma unroll
    for (int ks=0; ks<7; ks++) {              // K = 112 exact
      bf8v A = ld_frag(aP + ks*16);
      #pragma unroll
      for (int n=0;n<NCNT;n++)
        acc[n] = MFMA32(A, ld_frag(bP + n*32*SXS + ks*16), acc[n]);
    }
  }

  f4v at0 = (f4v){0.f,0.f,0.f,0.f}, at1 = (f4v){0.f,0.f,0.f,0.f};
  if (TAIL) {
    const ushort_t* bT  = Xs_ + (96 + l15)*SXS + q4*8;
    const ushort_t* aT0 = hS + (mt*32 + l15)*SHT + q4*8;
    const ushort_t* aT1 = aT0 + 16*SHT;
    #pragma unroll
    for (int kc=0; kc<4; kc++) {
      bf8v Bt = ld_frag(bT + kc*32);
      at0 = MFMA16(ld_frag(aT0 + kc*32), Bt, at0);
      at1 = MFMA16(ld_frag(aT1 + kc*32), Bt, at1);
    }
  }

  if (NCNT > 0) {
    #pragma unroll
    for (int n=0;n<NCNT;n++) {
      ushort_t* arow = aDst + ((nBase+n)*32 + l31)*SAB;
      #pragma unroll
      for (int q=0;q<4;q++) {
        uint2 pv;
        pv.x = pk2(acc[n][4*q+0], acc[n][4*q+1]);
        pv.y = pk2(acc[n][4*q+2], acc[n][4*q+3]);
        *(uint2*)(arow + mt*32 + 8*q + 4*h32) = pv;
      }
    }
  }
  if (TAIL) {
    ushort_t* arow = aDst + (96 + l15)*SAB;
    #pragma unroll
    for (int s=0;s<2;s++) {
      const f4v& a = s ? at1 : at0;
      uint2 pv; pv.x = pk2(a[0],a[1]); pv.y = pk2(a[2],a[3]);
      *(uint2*)(arow + mt*32 + s*16 + 4*q4) = pv;
    }
  }
}

__global__ void prep_weights(const float* __restrict__ W1, const float* __restrict__ W2,
                             const float* __restrict__ W3, const float* __restrict__ W4,
                             ushort_t* __restrict__ o)
{
  int i = blockIdx.x*256 + threadIdx.x;
  if (i < 32768) {                       // W1p [256][128], K zero-padded
    int r = i >> 7, c = i & 127;
    o[i] = (c < NODE) ? f2bf(W1[r*NODE + c]) : (ushort_t)0;
  } else if (i < 98304) {                // W2 [256][256]
    o[i] = f2bf(W2[i - 32768]);
  } else if (i < 131072) {               // W3 [128][256]
    o[i] = f2bf(W3[i - 98304]);
  } else if (i < 139264) {               // W4 [64][128]
    o[i] = f2bf(W4[i - 131072]);
  }
}

__global__ void __launch_bounds__(512, 2) gcn_kernel(
    const float* __restrict__ x, const ushort_t* __restrict__ wsp,
    const float* __restrict__ b1, const float* __restrict__ b2,
    const float* __restrict__ b3, const float* __restrict__ b4,
    const float* __restrict__ W5, const float* __restrict__ b5,
    const float* __restrict__ Wf, const float* __restrict__ bfc,
    float* __restrict__ out)
{
  extern __shared__ ushort_t smem[];
  ushort_t* Xs = smem;
  ushort_t* hT = smem + HT_OFF;
  ushort_t* aB = smem + AB_OFF;

  const int tid  = threadIdx.x;
  const int w    = tid >> 6;
  const int lane = tid & 63;

  // zero K-pad cols 112..127 of Xs and hT (read by MFMA16 tails; proj/agg
  // never write cols >= 112, so one-time zeroing suffices)
  for (int i = tid; i < 112*4; i += 512) {
    int r = i >> 2, g = i & 3;
    *(uint2*)(Xs + r*SXS + 112 + g*4) = make_uint2(0u, 0u);
  }
  for (int i = tid; i < 256*4; i += 512) {
    int r = i >> 2, g = i & 3;
    *(uint2*)(hT + r*SHT + 112 + g*4) = make_uint2(0u, 0u);
  }
  // stage X: fp32 global -> bf16 LDS (b64 packed writes)
  {
    const float4* x4 = (const float4*)(x + (size_t)blockIdx.x * (NODE*NODE));
    for (int i = tid; i < (NODE*NODE/4); i += 512) {
      float4 v = x4[i];
      int r = i / 28, c4 = (i - r*28) * 4;
      uint2 pv; pv.x = pk2(v.x, v.y); pv.y = pk2(v.z, v.w);
      *(uint2*)(Xs + r*SXS + c4) = pv;
    }
  }
  __syncthreads();

  // [p1 + a2] fused: F=256, 8 waves, wave = feat-tile (same-wave handoff)
  proj_part<7,4,SXS,3,true>(Xs, wsp, 128, b1, hT, w, 0, lane);
  agg_part<3,true>(hT, Xs, aB, w, 0, lane);
  __syncthreads();

  // [p2 + a3] fused: F=256, K=256
  proj_part<16,8,SAB,3,true>(aB, wsp + 32768, 256, b2, hT, w, 0, lane);
  agg_part<3,true>(hT, Xs, aB, w, 0, lane);
  __syncthreads();

  // p3: F=128, K=256 — 8 waves: ntile = w&3, node-half = w>>2
  {
    const int nt = w & 3, g = w >> 2;
    if (g == 0) proj_part<16,8,SAB,2,false>(aB, wsp + 98304, 256, b3, hT, nt, 0, lane);
    else        proj_part<16,8,SAB,1,true >(aB, wsp + 98304, 256, b3, hT, nt, 2, lane);
  }
  __syncthreads();
  // a4: 8 waves: mt = w&3, node-half = w>>2
  {
    const int mt = w & 3, g = w >> 2;
    if (g == 0) agg_part<2,false>(hT, Xs, aB, mt, 0, lane);
    else        agg_part<1,true >(hT, Xs, aB, mt, 2, lane);
  }
  __syncthreads();

  // p4: F=64, K=128 — 8 waves: ntile = w&1, node-quarter = w>>1
  {
    const int nt = w & 1, g = w >> 1;
    if (g < 3) proj_part<8,4,SAB,1,false>(aB, wsp + 131072, 128, b4, hT, nt, g, lane);
    else       proj_part<8,4,SAB,0,true >(aB, wsp + 131072, 128, b4, hT, nt, 0, lane);
  }
  __syncthreads();
  // a5: 8 waves: mt = w&1, node-quarter = w>>1
  {
    const int mt = w & 1, g = w >> 1;
    if (g < 3) agg_part<1,false>(hT, Xs, aB, mt, g, lane);
    else       agg_part<0,true >(hT, Xs, aB, mt, 0, lane);
  }
  __syncthreads();

  // final: h5[n] = relu(b5 + a5[n][:].W5); out = bf + sum_n h5[n]*Wf[n]
  float partial = 0.f;
  if (tid < NODE) {
    const ushort_t* row = aB + tid*SAB;
    float s = 0.f;
    #pragma unroll
    for (int k4 = 0; k4 < 16; k4++) {
      uint2 u = *(const uint2*)(row + k4*4);
      s += bf2f((ushort_t)(u.x & 0xFFFF)) * W5[k4*4+0];
      s += bf2f((ushort_t)(u.x >> 16))    * W5[k4*4+1];
      s += bf2f((ushort_t)(u.y & 0xFFFF)) * W5[k4*4+2];
      s += bf2f((ushort_t)(u.y >> 16))    * W5[k4*4+3];
    }
    s += b5[0];
    s = s > 0.f ? s : 0.f;
    partial = s * Wf[tid];
  }
  float* red = (float*)Xs;               // Xs dead after a5
  if (tid < 128) red[tid] = partial;     // lanes 112..127 write 0
  __syncthreads();
  if (w == 0) {
    float v = red[lane] + red[lane + 64];
    #pragma unroll
    for (int off = 32; off > 0; off >>= 1)
      v += __shfl_xor(v, off, 64);
    if (lane == 0) out[blockIdx.x] = v + bfc[0];
  }
}

extern "C" void kernel_launch(void* const* d_in, const int* in_sizes, int n_in,
                              void* d_out, int out_size, void* d_ws, size_t ws_size,
                              hipStream_t stream) {
  const float* x   = (const float*)d_in[0];
  const float* W1  = (const float*)d_in[1];
  const float* b1  = (const float*)d_in[2];
  const float* W2  = (const float*)d_in[3];
  const float* b2  = (const float*)d_in[4];
  const float* W3  = (const float*)d_in[5];
  const float* b3  = (const float*)d_in[6];
  const float* W4  = (const float*)d_in[7];
  const float* b4  = (const float*)d_in[8];
  const float* W5  = (const float*)d_in[9];
  const float* b5  = (const float*)d_in[10];
  const float* Wf  = (const float*)d_in[11];
  const float* bfc = (const float*)d_in[12];
  ushort_t* wsp = (ushort_t*)d_ws;
  float* out = (float*)d_out;

  prep_weights<<<544, 256, 0, stream>>>(W1, W2, W3, W4, wsp);

  (void)hipFuncSetAttribute((const void*)gcn_kernel,
                            hipFuncAttributeMaxDynamicSharedMemorySize, SMEM_BYTES);
  gcn_kernel<<<NBATCH, 512, SMEM_BYTES, stream>>>(x, wsp, b1, b2, b3, b4,
                                                  W5, b5, Wf, bfc, out);
}

// Round 3
// 595.533 us; speedup vs baseline: 1.1736x; 1.1736x over previous
//
#include <hip/hip_runtime.h>
#include <hip/hip_bf16.h>

// GCN_large R7: register-fused proj->agg, exchange via ds_bpermute(lane^32)
// (direction-unambiguous; replaces v_permlane32_swap_b32 whose operand
// semantics were the prime suspect in R6's absmax failure).
// hT eliminated: proj D-frag (col=lane&31=feat) converted in-register to
// agg A-frag (lane&31=feat, k=node). Node dim padded to 128 via
// allocated-junk rows (junk A-rows only affect discarded D-rows; junk
// B-rows only affect masked D-cols) -> uniform 32x32x16 MFMA, no tails,
// no zero-fill, K=112 exact (W1 stride 112).
// aB double-buffered (ping-pong) -> no WAR hazard; 5 compute barriers.
// LDS: Xs [112][136] @0, aB0 [112][264] @15232, aB1 [112][264] @44800,
// +16-row slack (junk reads by m=3/n=3 fragment lanes).

#define NODE 112
#define NBATCH 4096
#define SXS 136
#define SAB 264
#define AB0_OFF 15232                    // 112*136
#define AB1_OFF 44800                    // +112*264
#define SMEM_BYTES ((AB1_OFF + 128*SAB)*2)   // 157184 B (incl. slack)

typedef float  f4v   __attribute__((ext_vector_type(4)));
typedef float  f16v  __attribute__((ext_vector_type(16)));
typedef __bf16 bf8v  __attribute__((ext_vector_type(8)));
typedef short  s8v   __attribute__((ext_vector_type(8)));
typedef unsigned u4v __attribute__((ext_vector_type(4)));
typedef unsigned short ushort_t;

__device__ __forceinline__ ushort_t f2bf(float f) {
  union { float f; unsigned u; } v; v.f = f;
  unsigned r = v.u + 0x7FFFu + ((v.u >> 16) & 1u);   // RNE
  return (ushort_t)(r >> 16);
}
__device__ __forceinline__ float bf2f(ushort_t h) {
  union { unsigned u; float f; } v; v.u = ((unsigned)h) << 16; return v.f;
}
// HW bf16 convert (RNE) -- compiler emits v_cvt_pk_bf16_f32 for pairs
__device__ __forceinline__ unsigned pk2(float a, float b) {
  unsigned short ul = __builtin_bit_cast(unsigned short, (__bf16)a);
  unsigned short uh = __builtin_bit_cast(unsigned short, (__bf16)b);
  return (unsigned)ul | ((unsigned)uh << 16);
}
__device__ __forceinline__ bf8v ld_frag(const ushort_t* p) {
  s8v t = *(const s8v*)p;
  return __builtin_bit_cast(bf8v, t);
}
// exchange with lane^32 partner (unambiguous cross-half swap)
__device__ __forceinline__ unsigned xchg32(unsigned v, int lane) {
  return (unsigned)__builtin_amdgcn_ds_bpermute(((lane ^ 32) << 2), (int)v);
}
#define MFMA32(a,b,c) __builtin_amdgcn_mfma_f32_32x32x16_bf16((a),(b),(c),0,0,0)

// proj + relu + in-register transpose to agg-A fragments.
// D layout: node = (reg&3)+8*(reg>>2)+4*h32+32m, feat = lane&31.
// Agg A-frag k-chunk ks: lane(h32) needs nodes [16ks+8*h32, +8) as 4 dwords.
// Frag pair p (p=0..3) belongs to half (p>>1) and is P[requester_h][p&1]
// of that half -> each lane sends P[1-h][d], keeps P[h][d], places via
// half-dependent selects. ks=7 (nodes 112..127) discarded.
template<int KS>
__device__ __forceinline__ void proj_exch(
    const ushort_t* aSrc, int sa,
    const ushort_t* __restrict__ Wg, int WK,
    const float* __restrict__ bias, int nt, int lane, unsigned* fr)
{
  const int l31 = lane & 31, h32 = lane >> 5;
  const bool hiH = (h32 != 0);

  f16v acc[4];
  #pragma unroll
  for (int m=0;m<4;m++)
    #pragma unroll
    for (int r=0;r<16;r++) acc[m][r] = 0.f;

  const ushort_t* aP = aSrc + l31*sa + h32*8;
  const ushort_t* bP = Wg + (nt*32 + l31)*WK + h32*8;
  #pragma unroll
  for (int ks=0; ks<KS; ks++) {
    bf8v B = ld_frag(bP + ks*16);
    #pragma unroll
    for (int m=0;m<4;m++)
      acc[m] = MFMA32(ld_frag(aP + m*32*sa + ks*16), B, acc[m]);
  }

  const float bv = bias[nt*32 + l31];
  #pragma unroll
  for (int m=0;m<4;m++) {
    unsigned P[4][2];
    const int NQ = (m==3) ? 2 : 4;          // skip nodes 112..127
    #pragma unroll
    for (int q=0;q<4;q++) {
      if (q >= NQ) break;
      float v0 = fmaxf(acc[m][4*q+0]+bv, 0.f);
      float v1 = fmaxf(acc[m][4*q+1]+bv, 0.f);
      float v2 = fmaxf(acc[m][4*q+2]+bv, 0.f);
      float v3 = fmaxf(acc[m][4*q+3]+bv, 0.f);
      P[q][0] = pk2(v0, v1);
      P[q][1] = pk2(v2, v3);
    }
    // even frag ks=2m : nodes [32m, 32m+16), uses P[0],P[1]
    {
      unsigned s0 = hiH ? P[0][0] : P[1][0];
      unsigned s1 = hiH ? P[0][1] : P[1][1];
      unsigned r0 = xchg32(s0, lane);
      unsigned r1 = xchg32(s1, lane);
      unsigned o0 = hiH ? P[1][0] : P[0][0];
      unsigned o1 = hiH ? P[1][1] : P[0][1];
      fr[8*m+0] = hiH ? r0 : o0;
      fr[8*m+1] = hiH ? r1 : o1;
      fr[8*m+2] = hiH ? o0 : r0;
      fr[8*m+3] = hiH ? o1 : r1;
    }
    if (m < 3) {
      // odd frag ks=2m+1 : nodes [32m+16, 32m+32), uses P[2],P[3]
      unsigned s0 = hiH ? P[2][0] : P[3][0];
      unsigned s1 = hiH ? P[2][1] : P[3][1];
      unsigned r0 = xchg32(s0, lane);
      unsigned r1 = xchg32(s1, lane);
      unsigned o0 = hiH ? P[3][0] : P[2][0];
      unsigned o1 = hiH ? P[3][1] : P[2][1];
      fr[8*m+4] = hiH ? r0 : o0;
      fr[8*m+5] = hiH ? r1 : o1;
      fr[8*m+6] = hiH ? o0 : r0;
      fr[8*m+7] = hiH ? o1 : r1;
    }
  }
}

// agg: aDst[node][feat tile mt] = X . h, A-fragments from fr (registers),
// B = Xs rows (out-node major). n=3 stores masked to l31<16 (nodes 96..111).
__device__ __forceinline__ void agg_store(
    const unsigned* fr, const ushort_t* Xs_, ushort_t* aDst, int mt, int lane)
{
  const int l31 = lane & 31, h32 = lane >> 5;

  f16v acc[4];
  #pragma unroll
  for (int n=0;n<4;n++)
    #pragma unroll
    for (int r=0;r<16;r++) acc[n][r] = 0.f;

  const ushort_t* bP = Xs_ + l31*SXS + h32*8;
  #pragma unroll
  for (int ks=0; ks<7; ks++) {              // K = 112 exact
    u4v t = (u4v){fr[4*ks+0], fr[4*ks+1], fr[4*ks+2], fr[4*ks+3]};
    bf8v A = __builtin_bit_cast(bf8v, t);
    #pragma unroll
    for (int n=0;n<4;n++)
      acc[n] = MFMA32(A, ld_frag(bP + n*32*SXS + ks*16), acc[n]);
  }

  #pragma unroll
  for (int n=0;n<4;n++) {
    ushort_t* arow = aDst + (n*32 + l31)*SAB;
    bool on = (n < 3) || (l31 < 16);
    #pragma unroll
    for (int q=0;q<4;q++) {
      uint2 pv;
      pv.x = pk2(acc[n][4*q+0], acc[n][4*q+1]);
      pv.y = pk2(acc[n][4*q+2], acc[n][4*q+3]);
      if (on) *(uint2*)(arow + mt*32 + 8*q + 4*h32) = pv;
    }
  }
}

// weights, bf16: W1 [256][112] @0, W2 [256][256] @28672,
// W3 [128][256] @94208, W4 [64][128] @126976. total 135168 elems.
__global__ void prep_weights(const float* __restrict__ W1, const float* __restrict__ W2,
                             const float* __restrict__ W3, const float* __restrict__ W4,
                             ushort_t* __restrict__ o)
{
  int i = blockIdx.x*256 + threadIdx.x;
  if (i < 28672)       o[i] = f2bf(W1[i]);
  else if (i < 94208)  o[i] = f2bf(W2[i - 28672]);
  else if (i < 126976) o[i] = f2bf(W3[i - 94208]);
  else if (i < 135168) o[i] = f2bf(W4[i - 126976]);
}

__global__ void __launch_bounds__(512, 2) gcn_kernel(
    const float* __restrict__ x, const ushort_t* __restrict__ wsp,
    const float* __restrict__ b1, const float* __restrict__ b2,
    const float* __restrict__ b3, const float* __restrict__ b4,
    const float* __restrict__ W5, const float* __restrict__ b5,
    const float* __restrict__ Wf, const float* __restrict__ bfc,
    float* __restrict__ out)
{
  extern __shared__ ushort_t smem[];
  ushort_t* Xs  = smem;                // [112][136]
  ushort_t* aB0 = smem + AB0_OFF;      // [112][264]
  ushort_t* aB1 = smem + AB1_OFF;      // [112][264] + slack

  const int tid  = threadIdx.x;
  const int w    = tid >> 6;
  const int lane = tid & 63;

  // stage X: fp32 global -> bf16 LDS (no pads needed anywhere)
  {
    const float4* x4 = (const float4*)(x + (size_t)blockIdx.x * (NODE*NODE));
    for (int i = tid; i < (NODE*NODE/4); i += 512) {
      float4 v = x4[i];
      int r = i / 28, c4 = (i - r*28) * 4;
      uint2 pv; pv.x = pk2(v.x, v.y); pv.y = pk2(v.z, v.w);
      *(uint2*)(Xs + r*SXS + c4) = pv;
    }
  }
  __syncthreads();

  unsigned fr[28];

  // phase 1: h1 = relu(X.W1^T+b1) -> regs -> a2 = X.h1 -> aB0
  proj_exch<7>(Xs, SXS, wsp, 112, b1, w, lane, fr);
  agg_store(fr, Xs, aB0, w, lane);
  __syncthreads();

  // phase 2: F=256, K=256; reads aB0, writes aB1
  proj_exch<16>(aB0, SAB, wsp + 28672, 256, b2, w, lane, fr);
  agg_store(fr, Xs, aB1, w, lane);
  __syncthreads();

  // phase 3: F=128, K=256; waves 0..3; reads aB1, writes aB0
  if (w < 4) {
    proj_exch<16>(aB1, SAB, wsp + 94208, 256, b3, w, lane, fr);
    agg_store(fr, Xs, aB0, w, lane);
  }
  __syncthreads();

  // phase 4: F=64, K=128; waves 0..1; reads aB0, writes aB1
  if (w < 2) {
    proj_exch<8>(aB0, SAB, wsp + 126976, 128, b4, w, lane, fr);
    agg_store(fr, Xs, aB1, w, lane);
  }
  __syncthreads();

  // final: h5[n] = relu(b5 + a5[n][:].W5); out = bf + sum_n h5[n]*Wf[n]
  float partial = 0.f;
  if (tid < NODE) {
    const ushort_t* row = aB1 + tid*SAB;
    float s = 0.f;
    #pragma unroll
    for (int k4 = 0; k4 < 16; k4++) {
      uint2 u = *(const uint2*)(row + k4*4);
      s += bf2f((ushort_t)(u.x & 0xFFFF)) * W5[k4*4+0];
      s += bf2f((ushort_t)(u.x >> 16))    * W5[k4*4+1];
      s += bf2f((ushort_t)(u.y & 0xFFFF)) * W5[k4*4+2];
      s += bf2f((ushort_t)(u.y >> 16))    * W5[k4*4+3];
    }
    s += b5[0];
    s = s > 0.f ? s : 0.f;
    partial = s * Wf[tid];
  }
  float* red = (float*)Xs;               // Xs dead now
  if (tid < 128) red[tid] = partial;     // lanes 112..127 write 0
  __syncthreads();
  if (w == 0) {
    float v = red[lane] + red[lane + 64];
    #pragma unroll
    for (int off = 32; off > 0; off >>= 1)
      v += __shfl_xor(v, off, 64);
    if (lane == 0) out[blockIdx.x] = v + bfc[0];
  }
}

extern "C" void kernel_launch(void* const* d_in, const int* in_sizes, int n_in,
                              void* d_out, int out_size, void* d_ws, size_t ws_size,
                              hipStream_t stream) {
  const float* x   = (const float*)d_in[0];
  const float* W1  = (const float*)d_in[1];
  const float* b1  = (const float*)d_in[2];
  const float* W2  = (const float*)d_in[3];
  const float* b2  = (const float*)d_in[4];
  const float* W3  = (const float*)d_in[5];
  const float* b3  = (const float*)d_in[6];
  const float* W4  = (const float*)d_in[7];
  const float* b4  = (const float*)d_in[8];
  const float* W5  = (const float*)d_in[9];
  const float* b5  = (const float*)d_in[10];
  const float* Wf  = (const float*)d_in[11];
  const float* bfc = (const float*)d_in[12];
  ushort_t* wsp = (ushort_t*)d_ws;
  float* out = (float*)d_out;

  prep_weights<<<528, 256, 0, stream>>>(W1, W2, W3, W4, wsp);

  (void)hipFuncSetAttribute((const void*)gcn_kernel,
                            hipFuncAttributeMaxDynamicSharedMemorySize, SMEM_BYTES);
  gcn_kernel<<<NBATCH, 512, SMEM_BYTES, stream>>>(x, wsp, b1, b2, b3, b4,
                                                  W5, b5, Wf, bfc, out);
}

// Round 4
// 568.468 us; speedup vs baseline: 1.2295x; 1.0476x over previous
//
#include <hip/hip_runtime.h>
#include <hip/hip_bf16.h>

// GCN_large R8: X held in registers (28 x 16B frags/lane = 112 VGPR).
// proj-A (phase 1) and agg-B read X with identical lane->element mapping
// (row = t*32+l31, k = 16ks+8h32+j), so one register copy serves both.
// agg is now pure-register MFMA (zero LDS reads). LDS holds only the aB
// ping-pong (2 x [112][264] bf16 = 118KB); X staged through aB1 region
// once at start for coalesced load+convert, then frag-read into regs.
// Junk rows via address clamp (t=3/m=3: row 96+(l31&15)): duplicate rows
// feed only discarded D rows (proj) / masked D cols (agg) -- same
// argument as R7 (harness-verified). Exchange path (xchg32) unchanged.

#define NODE 112
#define NBATCH 4096
#define SXS 136
#define SAB 264
#define AB1_OFF 29568                    // 112*264
#define SMEM_BYTES (2*112*SAB*2)         // 118272 B

typedef float  f4v   __attribute__((ext_vector_type(4)));
typedef float  f16v  __attribute__((ext_vector_type(16)));
typedef __bf16 bf8v  __attribute__((ext_vector_type(8)));
typedef short  s8v   __attribute__((ext_vector_type(8)));
typedef unsigned u4v __attribute__((ext_vector_type(4)));
typedef unsigned short ushort_t;

__device__ __forceinline__ ushort_t f2bf(float f) {
  union { float f; unsigned u; } v; v.f = f;
  unsigned r = v.u + 0x7FFFu + ((v.u >> 16) & 1u);   // RNE
  return (ushort_t)(r >> 16);
}
__device__ __forceinline__ float bf2f(ushort_t h) {
  union { unsigned u; float f; } v; v.u = ((unsigned)h) << 16; return v.f;
}
__device__ __forceinline__ unsigned pk2(float a, float b) {
  unsigned short ul = __builtin_bit_cast(unsigned short, (__bf16)a);
  unsigned short uh = __builtin_bit_cast(unsigned short, (__bf16)b);
  return (unsigned)ul | ((unsigned)uh << 16);
}
__device__ __forceinline__ bf8v ld_frag(const ushort_t* p) {
  s8v t = *(const s8v*)p;
  return __builtin_bit_cast(bf8v, t);
}
// exchange with lane^32 partner (verified in R7)
__device__ __forceinline__ unsigned xchg32(unsigned v, int lane) {
  return (unsigned)__builtin_amdgcn_ds_bpermute(((lane ^ 32) << 2), (int)v);
}
#define MFMA32(a,b,c) __builtin_amdgcn_mfma_f32_32x32x16_bf16((a),(b),(c),0,0,0)

// Build agg-A fragments fr[28] from proj accumulators (+bias, relu).
// Identical to R7's verified epilogue.
__device__ __forceinline__ void exch_build(const f16v* acc, float bv, int lane,
                                           unsigned* fr)
{
  const bool hiH = (lane >> 5) != 0;
  #pragma unroll
  for (int m=0;m<4;m++) {
    unsigned P[4][2];
    const int NQ = (m==3) ? 2 : 4;          // skip nodes 112..127
    #pragma unroll
    for (int q=0;q<4;q++) {
      if (q >= NQ) break;
      float v0 = fmaxf(acc[m][4*q+0]+bv, 0.f);
      float v1 = fmaxf(acc[m][4*q+1]+bv, 0.f);
      float v2 = fmaxf(acc[m][4*q+2]+bv, 0.f);
      float v3 = fmaxf(acc[m][4*q+3]+bv, 0.f);
      P[q][0] = pk2(v0, v1);
      P[q][1] = pk2(v2, v3);
    }
    {
      unsigned s0 = hiH ? P[0][0] : P[1][0];
      unsigned s1 = hiH ? P[0][1] : P[1][1];
      unsigned r0 = xchg32(s0, lane);
      unsigned r1 = xchg32(s1, lane);
      unsigned o0 = hiH ? P[1][0] : P[0][0];
      unsigned o1 = hiH ? P[1][1] : P[0][1];
      fr[8*m+0] = hiH ? r0 : o0;
      fr[8*m+1] = hiH ? r1 : o1;
      fr[8*m+2] = hiH ? o0 : r0;
      fr[8*m+3] = hiH ? o1 : r1;
    }
    if (m < 3) {
      unsigned s0 = hiH ? P[2][0] : P[3][0];
      unsigned s1 = hiH ? P[2][1] : P[3][1];
      unsigned r0 = xchg32(s0, lane);
      unsigned r1 = xchg32(s1, lane);
      unsigned o0 = hiH ? P[3][0] : P[2][0];
      unsigned o1 = hiH ? P[3][1] : P[2][1];
      fr[8*m+4] = hiH ? r0 : o0;
      fr[8*m+5] = hiH ? r1 : o1;
      fr[8*m+6] = hiH ? o0 : r0;
      fr[8*m+7] = hiH ? o1 : r1;
    }
  }
}

// phase-1 proj: A = X register frags, B = W1 (global). K = 112 exact.
__device__ __forceinline__ void proj1_exch(
    const bf8v* Xr, const ushort_t* __restrict__ Wg,
    const float* __restrict__ bias, int nt, int lane, unsigned* fr)
{
  const int l31 = lane & 31, h32 = lane >> 5;
  f16v acc[4];
  #pragma unroll
  for (int m=0;m<4;m++)
    #pragma unroll
    for (int r=0;r<16;r++) acc[m][r] = 0.f;

  const ushort_t* bP = Wg + (nt*32 + l31)*112 + h32*8;
  #pragma unroll
  for (int ks=0; ks<7; ks++) {
    bf8v B = ld_frag(bP + ks*16);
    #pragma unroll
    for (int m=0;m<4;m++)
      acc[m] = MFMA32(Xr[m*7+ks], B, acc[m]);
  }
  exch_build(acc, bias[nt*32 + l31], lane, fr);
}

// phases 2-4 proj: A = aB (LDS, stride SAB), B = W (global, stride WK).
// m=3 rows clamped to 96+(l31&15): duplicate rows feed only discarded
// D rows 112..127.
template<int KS>
__device__ __forceinline__ void proj_exch(
    const ushort_t* aSrc, const ushort_t* __restrict__ Wg, int WK,
    const float* __restrict__ bias, int nt, int lane, unsigned* fr)
{
  const int l31 = lane & 31, h32 = lane >> 5;
  f16v acc[4];
  #pragma unroll
  for (int m=0;m<4;m++)
    #pragma unroll
    for (int r=0;r<16;r++) acc[m][r] = 0.f;

  const ushort_t* aP  = aSrc + l31*SAB + h32*8;
  const ushort_t* aP3 = aSrc + (96 + (l31 & 15))*SAB + h32*8;
  const ushort_t* bP  = Wg + (nt*32 + l31)*WK + h32*8;
  #pragma unroll
  for (int ks=0; ks<KS; ks++) {
    bf8v B = ld_frag(bP + ks*16);
    acc[0] = MFMA32(ld_frag(aP +            ks*16), B, acc[0]);
    acc[1] = MFMA32(ld_frag(aP + 32*SAB +   ks*16), B, acc[1]);
    acc[2] = MFMA32(ld_frag(aP + 64*SAB +   ks*16), B, acc[2]);
    acc[3] = MFMA32(ld_frag(aP3 +           ks*16), B, acc[3]);
  }
  exch_build(acc, bias[nt*32 + l31], lane, fr);
}

// agg: pure-register MFMA. A = fr, B = Xr. Stores aB[node][feat tile mt];
// n=3 cols masked to l31<16 (nodes 96..111).
__device__ __forceinline__ void agg_store(
    const unsigned* fr, const bf8v* Xr, ushort_t* aDst, int mt, int lane)
{
  const int l31 = lane & 31, h32 = lane >> 5;
  f16v acc[4];
  #pragma unroll
  for (int n=0;n<4;n++)
    #pragma unroll
    for (int r=0;r<16;r++) acc[n][r] = 0.f;

  #pragma unroll
  for (int ks=0; ks<7; ks++) {              // K = 112 exact
    u4v t = (u4v){fr[4*ks+0], fr[4*ks+1], fr[4*ks+2], fr[4*ks+3]};
    bf8v A = __builtin_bit_cast(bf8v, t);
    #pragma unroll
    for (int n=0;n<4;n++)
      acc[n] = MFMA32(A, Xr[n*7+ks], acc[n]);
  }

  #pragma unroll
  for (int n=0;n<4;n++) {
    ushort_t* arow = aDst + (n*32 + l31)*SAB;
    bool on = (n < 3) || (l31 < 16);
    #pragma unroll
    for (int q=0;q<4;q++) {
      uint2 pv;
      pv.x = pk2(acc[n][4*q+0], acc[n][4*q+1]);
      pv.y = pk2(acc[n][4*q+2], acc[n][4*q+3]);
      if (on) *(uint2*)(arow + mt*32 + 8*q + 4*h32) = pv;
    }
  }
}

// weights, bf16: W1 [256][112] @0, W2 [256][256] @28672,
// W3 [128][256] @94208, W4 [64][128] @126976. total 135168 elems.
__global__ void prep_weights(const float* __restrict__ W1, const float* __restrict__ W2,
                             const float* __restrict__ W3, const float* __restrict__ W4,
                             ushort_t* __restrict__ o)
{
  int i = blockIdx.x*256 + threadIdx.x;
  if (i < 28672)       o[i] = f2bf(W1[i]);
  else if (i < 94208)  o[i] = f2bf(W2[i - 28672]);
  else if (i < 126976) o[i] = f2bf(W3[i - 94208]);
  else if (i < 135168) o[i] = f2bf(W4[i - 126976]);
}

__global__ void __launch_bounds__(512, 2) gcn_kernel(
    const float* __restrict__ x, const ushort_t* __restrict__ wsp,
    const float* __restrict__ b1, const float* __restrict__ b2,
    const float* __restrict__ b3, const float* __restrict__ b4,
    const float* __restrict__ W5, const float* __restrict__ b5,
    const float* __restrict__ Wf, const float* __restrict__ bfc,
    float* __restrict__ out)
{
  extern __shared__ ushort_t smem[];
  ushort_t* aB0 = smem;                // [112][264]
  ushort_t* aB1 = smem + AB1_OFF;      // [112][264]

  const int tid  = threadIdx.x;
  const int w    = tid >> 6;
  const int lane = tid & 63;
  const int l31  = lane & 31, h32 = lane >> 5;

  // stage X (fp32 -> bf16) into aB1 region (stride 136), coalesced
  {
    ushort_t* Xstg = aB1;
    const float4* x4 = (const float4*)(x + (size_t)blockIdx.x * (NODE*NODE));
    for (int i = tid; i < (NODE*NODE/4); i += 512) {
      float4 v = x4[i];
      int r = i / 28, c4 = (i - r*28) * 4;
      uint2 pv; pv.x = pk2(v.x, v.y); pv.y = pk2(v.z, v.w);
      *(uint2*)(Xstg + r*SXS + c4) = pv;
    }
  }
  __syncthreads();

  // X -> registers: Xr[t*7+ks] = X[row(t)][16ks+8h32 .. +8)
  // t=3 rows clamped (duplicates feed only discarded/masked outputs)
  bf8v Xr[28];
  {
    const ushort_t* Xstg = aB1;
    #pragma unroll
    for (int t=0;t<4;t++) {
      int row = (t < 3) ? (t*32 + l31) : (96 + (l31 & 15));
      const ushort_t* rp = Xstg + row*SXS + h32*8;
      #pragma unroll
      for (int ks=0;ks<7;ks++)
        Xr[t*7+ks] = ld_frag(rp + ks*16);
    }
  }
  __syncthreads();   // all frag reads done before aB1 is overwritten (p2 agg)

  unsigned fr[28];

  // phase 1: h1 = relu(X.W1^T+b1) -> regs -> a2 = X.h1 -> aB0
  proj1_exch(Xr, wsp, b1, w, lane, fr);
  agg_store(fr, Xr, aB0, w, lane);
  __syncthreads();

  // phase 2: F=256, K=256; reads aB0, writes aB1
  proj_exch<16>(aB0, wsp + 28672, 256, b2, w, lane, fr);
  agg_store(fr, Xr, aB1, w, lane);
  __syncthreads();

  // phase 3: F=128, K=256; waves 0..3; reads aB1, writes aB0
  if (w < 4) {
    proj_exch<16>(aB1, wsp + 94208, 256, b3, w, lane, fr);
    agg_store(fr, Xr, aB0, w, lane);
  }
  __syncthreads();

  // phase 4: F=64, K=128; waves 0..1; reads aB0, writes aB1
  if (w < 2) {
    proj_exch<8>(aB0, wsp + 126976, 128, b4, w, lane, fr);
    agg_store(fr, Xr, aB1, w, lane);
  }
  __syncthreads();

  // final: h5[n] = relu(b5 + a5[n][:].W5); out = bf + sum_n h5[n]*Wf[n]
  float partial = 0.f;
  if (tid < NODE) {
    const ushort_t* row = aB1 + tid*SAB;
    float s = 0.f;
    #pragma unroll
    for (int k4 = 0; k4 < 16; k4++) {
      uint2 u = *(const uint2*)(row + k4*4);
      s += bf2f((ushort_t)(u.x & 0xFFFF)) * W5[k4*4+0];
      s += bf2f((ushort_t)(u.x >> 16))    * W5[k4*4+1];
      s += bf2f((ushort_t)(u.y & 0xFFFF)) * W5[k4*4+2];
      s += bf2f((ushort_t)(u.y >> 16))    * W5[k4*4+3];
    }
    s += b5[0];
    s = s > 0.f ? s : 0.f;
    partial = s * Wf[tid];
  }
  float* red = (float*)aB0;              // aB0 dead now
  __syncthreads();                       // aB1 reads done before red overlaps? (red uses aB0 only; barrier orders red writes)
  if (tid < 128) red[tid] = partial;     // lanes 112..127 write 0
  __syncthreads();
  if (w == 0) {
    float v = red[lane] + red[lane + 64];
    #pragma unroll
    for (int off = 32; off > 0; off >>= 1)
      v += __shfl_xor(v, off, 64);
    if (lane == 0) out[blockIdx.x] = v + bfc[0];
  }
}

extern "C" void kernel_launch(void* const* d_in, const int* in_sizes, int n_in,
                              void* d_out, int out_size, void* d_ws, size_t ws_size,
                              hipStream_t stream) {
  const float* x   = (const float*)d_in[0];
  const float* W1  = (const float*)d_in[1];
  const float* b1  = (const float*)d_in[2];
  const float* W2  = (const float*)d_in[3];
  const float* b2  = (const float*)d_in[4];
  const float* W3  = (const float*)d_in[5];
  const float* b3  = (const float*)d_in[6];
  const float* W4  = (const float*)d_in[7];
  const float* b4  = (const float*)d_in[8];
  const float* W5  = (const float*)d_in[9];
  const float* b5  = (const float*)d_in[10];
  const float* Wf  = (const float*)d_in[11];
  const float* bfc = (const float*)d_in[12];
  ushort_t* wsp = (ushort_t*)d_ws;
  float* out = (float*)d_out;

  prep_weights<<<528, 256, 0, stream>>>(W1, W2, W3, W4, wsp);

  (void)hipFuncSetAttribute((const void*)gcn_kernel,
                            hipFuncAttributeMaxDynamicSharedMemorySize, SMEM_BYTES);
  gcn_kernel<<<NBATCH, 512, SMEM_BYTES, stream>>>(x, wsp, b1, b2, b3, b4,
                                                  W5, b5, Wf, bfc, out);
}